// Round 1
// baseline (237.318 us; speedup 1.0000x reference)
//
#include <hip/hip_runtime.h>
#include <stdint.h>
#include <stddef.h>

#define VV 3
#define NN 4096
#define DD 512
#define CC 10

typedef unsigned short bf16_t;
typedef __attribute__((ext_vector_type(8))) short bf16x8;
typedef __attribute__((ext_vector_type(4))) float f32x4;
typedef __attribute__((ext_vector_type(4))) int i32x4;
typedef __attribute__((ext_vector_type(4))) unsigned short u16x4;

#define MFMA16 __builtin_amdgcn_mfma_f32_16x16x32_bf16

__device__ __forceinline__ float bf2f(bf16_t u) {
  union { unsigned u; float f; } c; c.u = ((unsigned)u) << 16; return c.f;
}
__device__ __forceinline__ bf16_t f2bf(float f) {
  union { float f; unsigned u; } c; c.f = f;
  unsigned r = (c.u + 0x7FFFu + ((c.u >> 16) & 1u)) >> 16;
  return (bf16_t)r;
}
__device__ __forceinline__ float splus(float x) {
  float ax = fabsf(x);
  return fmaxf(x, 0.0f) + log1pf(expf(-ax));
}
// encode 2 adjacency values (bit + diag) in {0,1,2} as packed bf16 pair
__device__ __forceinline__ unsigned pack2(unsigned bits, unsigned dmask, int b) {
  unsigned s0 = ((bits >> b) & 1u) + ((dmask >> b) & 1u);
  unsigned s1 = ((bits >> (b + 1)) & 1u) + ((dmask >> (b + 1)) & 1u);
  unsigned lo = s0 ? (0x3F00u + (s0 << 7)) : 0u;
  unsigned hi = s1 ? (0x3F00u + (s1 << 7)) : 0u;
  return lo | (hi << 16);
}

// ---------------- K1: A (f32, binary) -> bitmask + dinv = 1/sqrt(deg) -------
__global__ __launch_bounds__(256) void k_mask(const float* __restrict__ A,
    unsigned long long* __restrict__ mask, float* __restrict__ dinv)
{
  int wid = blockIdx.x * 4 + (threadIdx.x >> 6);   // row id in [0, V*N)
  int lane = threadIdx.x & 63;
  const float4* r4 = (const float4*)(A + (size_t)wid * NN + lane * 64);
  unsigned long long bits = 0ull;
#pragma unroll
  for (int q = 0; q < 16; ++q) {
    float4 x = r4[q];
    bits |= ((unsigned long long)(x.x != 0.0f)) << (q * 4 + 0);
    bits |= ((unsigned long long)(x.y != 0.0f)) << (q * 4 + 1);
    bits |= ((unsigned long long)(x.z != 0.0f)) << (q * 4 + 2);
    bits |= ((unsigned long long)(x.w != 0.0f)) << (q * 4 + 3);
  }
  mask[(size_t)wid * 64 + lane] = bits;
  int pc = __popcll(bits);
#pragma unroll
  for (int s = 32; s; s >>= 1) pc += __shfl_xor(pc, s);
  if (lane == 0) dinv[wid] = 1.0f / sqrtf((float)(pc + 1));  // deg = popcnt + 1 (the +I)
}

// ---------------- K2: Xs_t[v][d][j] = dinv_j * X[v][j][d] (bf16), X_bf ------
__global__ __launch_bounds__(256) void k_xpose(const float* __restrict__ X,
    const float* __restrict__ dinv, bf16_t* __restrict__ Xs_t, bf16_t* __restrict__ X_bf)
{
  __shared__ float tile[64][65];
  int v = blockIdx.z;
  int jb = blockIdx.x * 64, db = blockIdx.y * 64;
  int t = threadIdx.x;
  int tr = t >> 4, tc = (t & 15) * 4;
  const float* Xv = X + (size_t)v * NN * DD;
#pragma unroll
  for (int it = 0; it < 4; ++it) {
    int r = it * 16 + tr;
    int j = jb + r;
    float4 x = *(const float4*)(Xv + (size_t)j * DD + db + tc);
    u16x4 ob = { f2bf(x.x), f2bf(x.y), f2bf(x.z), f2bf(x.w) };
    *(u16x4*)(X_bf + (size_t)v * NN * DD + (size_t)j * DD + db + tc) = ob;
    float s = dinv[v * NN + j];
    tile[r][tc + 0] = x.x * s; tile[r][tc + 1] = x.y * s;
    tile[r][tc + 2] = x.z * s; tile[r][tc + 3] = x.w * s;
  }
  __syncthreads();
#pragma unroll
  for (int it = 0; it < 4; ++it) {
    int r = it * 16 + tr;     // d-local
    int d = db + r;
    u16x4 ob = { f2bf(tile[tc + 0][r]), f2bf(tile[tc + 1][r]),
                 f2bf(tile[tc + 2][r]), f2bf(tile[tc + 3][r]) };
    *(u16x4*)(Xs_t + (size_t)v * DD * NN + (size_t)d * NN + jb + tc) = ob;
  }
}

// ---------------- K4: Wc_t = (W1@W2)^T (bf16, padded to 16 rows), bp = b1@W2 -
__global__ __launch_bounds__(256) void k_wc(const float* __restrict__ W1,
    const float* __restrict__ b1, const float* __restrict__ W2,
    bf16_t* __restrict__ Wc_t, float* __restrict__ bp)
{
  int wid = blockIdx.x * 4 + (threadIdx.x >> 6);
  int lane = threadIdx.x & 63;
  if (wid >= VV * 513) return;
  int v = wid / 513, dd2 = wid % 513;
  const float* w2 = W2 + (size_t)v * DD * CC;
  const float* src = (dd2 < DD) ? (W1 + ((size_t)v * DD + dd2) * DD) : (b1 + (size_t)v * DD);
  float acc[CC];
#pragma unroll
  for (int c = 0; c < CC; ++c) acc[c] = 0.f;
  for (int it = 0; it < 8; ++it) {
    int e = it * 64 + lane;
    float w = src[e];
    const float* w2r = w2 + (size_t)e * CC;
#pragma unroll
    for (int c = 0; c < CC; ++c) acc[c] += w * w2r[c];
  }
#pragma unroll
  for (int c = 0; c < CC; ++c) {
#pragma unroll
    for (int s = 32; s; s >>= 1) acc[c] += __shfl_xor(acc[c], s);
  }
  if (lane == 0) {
    if (dd2 < DD) {
#pragma unroll
      for (int c = 0; c < CC; ++c) Wc_t[((size_t)v * 16 + c) * DD + dd2] = f2bf(acc[c]);
#pragma unroll
      for (int c = CC; c < 16; ++c) Wc_t[((size_t)v * 16 + c) * DD + dd2] = 0;
    } else {
#pragma unroll
      for (int c = 0; c < CC; ++c) bp[v * CC + c] = acc[c];
    }
  }
}

// ---------------- K4b: Wm_t = W_mlp^T (bf16, padded to 16 rows) -------------
__global__ __launch_bounds__(256) void k_wm(const float* __restrict__ W_mlp,
                                            bf16_t* __restrict__ Wm_t)
{
  int idx = blockIdx.x * 256 + threadIdx.x;
  if (idx >= VV * DD) return;
  int v = idx / DD, d = idx % DD;
#pragma unroll
  for (int c = 0; c < CC; ++c)
    Wm_t[((size_t)v * 16 + c) * DD + d] = f2bf(W_mlp[((size_t)v * DD + d) * CC + c]);
#pragma unroll
  for (int c = CC; c < 16; ++c) Wm_t[((size_t)v * 16 + c) * DD + d] = 0;
}

// ---------------- K3: H0 = Dinv (A+I) Dinv X  (bitmask-A bf16 MFMA GEMM) ----
#define BM 128
#define BN 128
#define BK 64
#define LDT 72                 // padded LDS row stride (bf16): 144B = 9*16B, conflict-light
#define KTILES (NN / BK)

__global__ __launch_bounds__(256, 2) void k_gemm(
    const unsigned* __restrict__ mask32, const bf16_t* __restrict__ Xs_t,
    const float* __restrict__ dinv, bf16_t* __restrict__ H0)
{
  __shared__ bf16_t Ab[2][BM * LDT];
  __shared__ bf16_t Bb[2][BM * LDT];
  int v = blockIdx.z, rowblk = blockIdx.y, colblk = blockIdx.x;
  int t = threadIdx.x;
  int w = t >> 6, lane = t & 63;
  int fl = lane & 15, fh = lane >> 4;

  const unsigned* mrow = mask32 + ((size_t)v * NN + (size_t)rowblk * BM) * (NN / 32);
  const bf16_t* Bsrc = Xs_t + ((size_t)v * DD + (size_t)colblk * BN) * NN;

  int er = t >> 1, eh = t & 1;            // A-expansion: row / 32-col half
  int gi = rowblk * BM + er;              // global row (for +I diagonal)
  int brow = t >> 3;                      // B staging: 0..31
  int bcol = (t & 7) * 8;

  f32x4 acc[4][4];
#pragma unroll
  for (int m = 0; m < 4; ++m)
#pragma unroll
    for (int n = 0; n < 4; ++n) { f32x4 z = {0.f, 0.f, 0.f, 0.f}; acc[m][n] = z; }

  bf16x8 br0, br1, br2, br3;
  unsigned mbits;

#define M_LOAD(kt_) do { mbits = mrow[(size_t)er * (NN / 32) + (kt_) * 2 + eh]; } while (0)
#define B_LOAD(kt_) do { \
    const bf16_t* bq_ = Bsrc + (size_t)brow * NN + (size_t)(kt_) * BK + bcol; \
    br0 = *(const bf16x8*)(bq_); \
    br1 = *(const bf16x8*)(bq_ + (size_t)32 * NN); \
    br2 = *(const bf16x8*)(bq_ + (size_t)64 * NN); \
    br3 = *(const bf16x8*)(bq_ + (size_t)96 * NN); \
  } while (0)
#define B_WRITE(buf_) do { \
    bf16_t* bw_ = &Bb[buf_][brow * LDT + bcol]; \
    *(bf16x8*)(bw_) = br0; \
    *(bf16x8*)(bw_ + 32 * LDT) = br1; \
    *(bf16x8*)(bw_ + 64 * LDT) = br2; \
    *(bf16x8*)(bw_ + 96 * LDT) = br3; \
  } while (0)
#define A_EXPAND(buf_, kt_) do { \
    int dpos_ = gi - (kt_) * 64 - eh * 32; \
    unsigned dmask_ = (dpos_ >= 0 && dpos_ < 32) ? (1u << dpos_) : 0u; \
    bf16_t* aw_ = &Ab[buf_][er * LDT + eh * 32]; \
    i32x4 o0_ = { (int)pack2(mbits, dmask_, 0),  (int)pack2(mbits, dmask_, 2),  (int)pack2(mbits, dmask_, 4),  (int)pack2(mbits, dmask_, 6)  }; \
    i32x4 o1_ = { (int)pack2(mbits, dmask_, 8),  (int)pack2(mbits, dmask_, 10), (int)pack2(mbits, dmask_, 12), (int)pack2(mbits, dmask_, 14) }; \
    i32x4 o2_ = { (int)pack2(mbits, dmask_, 16), (int)pack2(mbits, dmask_, 18), (int)pack2(mbits, dmask_, 20), (int)pack2(mbits, dmask_, 22) }; \
    i32x4 o3_ = { (int)pack2(mbits, dmask_, 24), (int)pack2(mbits, dmask_, 26), (int)pack2(mbits, dmask_, 28), (int)pack2(mbits, dmask_, 30) }; \
    *(i32x4*)(aw_ + 0)  = o0_; \
    *(i32x4*)(aw_ + 8)  = o1_; \
    *(i32x4*)(aw_ + 16) = o2_; \
    *(i32x4*)(aw_ + 24) = o3_; \
  } while (0)

  M_LOAD(0); B_LOAD(0);
  A_EXPAND(0, 0); B_WRITE(0);
  __syncthreads();
  int buf = 0;
  for (int kt = 0; kt < KTILES; ++kt) {
    if (kt + 1 < KTILES) { M_LOAD(kt + 1); B_LOAD(kt + 1); }
    {
      const bf16_t* Ap = &Ab[buf][((w >> 1) * 64) * LDT];
      const bf16_t* Bp = &Bb[buf][((w & 1) * 64) * LDT];
#pragma unroll
      for (int ks = 0; ks < 2; ++ks) {
        const int ko = ks * 32 + fh * 8;
        bf16x8 af[4], bfr[4];
#pragma unroll
        for (int m = 0; m < 4; ++m) af[m] = *(const bf16x8*)(Ap + (m * 16 + fl) * LDT + ko);
#pragma unroll
        for (int n = 0; n < 4; ++n) bfr[n] = *(const bf16x8*)(Bp + (n * 16 + fl) * LDT + ko);
#pragma unroll
        for (int m = 0; m < 4; ++m)
#pragma unroll
          for (int n = 0; n < 4; ++n)
            acc[m][n] = MFMA16(af[m], bfr[n], acc[m][n], 0, 0, 0);
      }
    }
    if (kt + 1 < KTILES) { A_EXPAND(buf ^ 1, kt + 1); B_WRITE(buf ^ 1); }
    __syncthreads();
    buf ^= 1;
  }

  // epilogue: scale row i by dinv_i, store bf16
  int gr0 = rowblk * BM + (w >> 1) * 64;
  int gc0 = colblk * BN + (w & 1) * 64;
  bf16_t* Hv = H0 + (size_t)v * NN * DD;
  const float* dv = dinv + v * NN;
#pragma unroll
  for (int m = 0; m < 4; ++m) {
    int r = gr0 + m * 16 + fh * 4;
    float d0 = dv[r], d1 = dv[r + 1], d2 = dv[r + 2], d3 = dv[r + 3];
#pragma unroll
    for (int n = 0; n < 4; ++n) {
      int c = gc0 + n * 16 + fl;
      f32x4 a = acc[m][n];
      Hv[(size_t)(r + 0) * DD + c] = f2bf(a[0] * d0);
      Hv[(size_t)(r + 1) * DD + c] = f2bf(a[1] * d1);
      Hv[(size_t)(r + 2) * DD + c] = f2bf(a[2] * d2);
      Hv[(size_t)(r + 3) * DD + c] = f2bf(a[3] * d3);
    }
  }
}

// ---------------- K5: Ps = dinv .* (H0@Wc + bp) ; mlp = softplus(X@Wm + bm) -
__global__ __launch_bounds__(256) void k_small(
    const bf16_t* __restrict__ H0, const bf16_t* __restrict__ X_bf,
    const bf16_t* __restrict__ Wc_t, const bf16_t* __restrict__ Wm_t,
    const float* __restrict__ bp, const float* __restrict__ b_mlp,
    const float* __restrict__ dinv, float* __restrict__ Ps_g, float* __restrict__ mlp_g)
{
  __shared__ bf16_t Bc[16 * 520];
  __shared__ bf16_t Bm[16 * 520];
  int v = blockIdx.y;
  int t = threadIdx.x;
  {
    int r = t & 15, ch = t >> 4;
    const bf16_t* sc = Wc_t + (size_t)v * 16 * DD + (size_t)r * DD + ch * 32;
    const bf16_t* sm = Wm_t + (size_t)v * 16 * DD + (size_t)r * DD + ch * 32;
    bf16_t* dc = &Bc[r * 520 + ch * 32];
    bf16_t* dm = &Bm[r * 520 + ch * 32];
#pragma unroll
    for (int q = 0; q < 4; ++q) {
      *(bf16x8*)(dc + q * 8) = *(const bf16x8*)(sc + q * 8);
      *(bf16x8*)(dm + q * 8) = *(const bf16x8*)(sm + q * 8);
    }
  }
  __syncthreads();
  int w = t >> 6, lane = t & 63;
  int fl = lane & 15, fh = lane >> 4;
  int r0 = blockIdx.x * 64 + w * 16;
  const bf16_t* Arow = H0 + ((size_t)v * NN + r0 + fl) * DD;
  const bf16_t* Xrow = X_bf + ((size_t)v * NN + r0 + fl) * DD;
  f32x4 aP = {0.f, 0.f, 0.f, 0.f}, aM = {0.f, 0.f, 0.f, 0.f};
#pragma unroll
  for (int k = 0; k < 16; ++k) {
    bf16x8 a1 = *(const bf16x8*)(Arow + k * 32 + fh * 8);
    bf16x8 b1v = *(const bf16x8*)(&Bc[fl * 520 + k * 32 + fh * 8]);
    aP = MFMA16(a1, b1v, aP, 0, 0, 0);
    bf16x8 a2 = *(const bf16x8*)(Xrow + k * 32 + fh * 8);
    bf16x8 b2v = *(const bf16x8*)(&Bm[fl * 520 + k * 32 + fh * 8]);
    aM = MFMA16(a2, b2v, aM, 0, 0, 0);
  }
  if (fl < CC) {
    float bpv = bp[v * CC + fl];
    float bmv = b_mlp[v * CC + fl];
#pragma unroll
    for (int g = 0; g < 4; ++g) {
      int j = r0 + fh * 4 + g;
      float dj = dinv[v * NN + j];
      Ps_g[((size_t)v * CC + fl) * NN + j] = (aP[g] + bpv) * dj;
      mlp_g[((size_t)v * NN + j) * CC + fl] = splus(aM[g] + bmv);
    }
  }
}

// ---------------- K6: E = consensus + mlp + softplus(dinv_i*(Ahat@Ps) + b2) -
__global__ __launch_bounds__(256) void k_spmm(
    const unsigned long long* __restrict__ mask, const float* __restrict__ Ps_g,
    const float* __restrict__ mlp_g, const float* __restrict__ consensus,
    const float* __restrict__ b2, const float* __restrict__ dinv,
    float* __restrict__ E)
{
  __shared__ bf16_t PsL[CC * NN];   // 80 KB, [c][j]
  int v = blockIdx.y;
  int t = threadIdx.x;
  const float* Pv = Ps_g + (size_t)v * CC * NN;
  for (int q = 0; q < (CC * NN) / 256; ++q) {
    int idx = q * 256 + t;
    PsL[idx] = f2bf(Pv[idx]);
  }
  __syncthreads();
  int w = t >> 6, lane = t & 63;
  int i0 = blockIdx.x * 32 + w * 8;
  for (int rr = 0; rr < 8; ++rr) {
    int i = i0 + rr;
    unsigned long long bits = mask[((size_t)v * NN + i) * 64 + lane];
    float acc[CC];
#pragma unroll
    for (int c = 0; c < CC; ++c) acc[c] = 0.f;
    while (bits) {
      int b = __builtin_ctzll(bits);
      bits &= bits - 1;
      int j = lane * 64 + b;
#pragma unroll
      for (int c = 0; c < CC; ++c) acc[c] += bf2f(PsL[c * NN + j]);
    }
#pragma unroll
    for (int c = 0; c < CC; ++c) {
#pragma unroll
      for (int s = 32; s; s >>= 1) acc[c] += __shfl_xor(acc[c], s);
    }
    if (lane == 0) {
      float di = dinv[v * NN + i];
      const float* cons = consensus + ((size_t)v * NN + i) * CC;
      const float* ml = mlp_g + ((size_t)v * NN + i) * CC;
      float* Eo = E + ((size_t)v * NN + i) * CC;
#pragma unroll
      for (int c = 0; c < CC; ++c) {
        float s2 = acc[c] + bf2f(PsL[c * NN + i]);   // + I * Ps_i
        Eo[c] = cons[c] + ml[c] + splus(di * s2 + b2[v * CC + c]);
      }
    }
  }
}

// ---------------- K7a: per-block partial sums of pairwise cosine dots -------
__global__ __launch_bounds__(256) void k_sim(const float* __restrict__ E,
                                             float* __restrict__ partial)
{
  __shared__ float sm[3][256];
  int t = threadIdx.x;
  int n = blockIdx.x * 256 + t;
  float e0[CC], e1[CC], e2[CC];
#pragma unroll
  for (int c = 0; c < CC; ++c) {
    e0[c] = E[(size_t)(0 * NN + n) * CC + c];
    e1[c] = E[(size_t)(1 * NN + n) * CC + c];
    e2[c] = E[(size_t)(2 * NN + n) * CC + c];
  }
  float n0 = 0, n1 = 0, n2 = 0, d01 = 0, d02 = 0, d12 = 0;
#pragma unroll
  for (int c = 0; c < CC; ++c) { n0 += e0[c]*e0[c]; n1 += e1[c]*e1[c]; n2 += e2[c]*e2[c]; }
  float i0 = 1.0f / fmaxf(sqrtf(n0), 1e-8f);
  float i1 = 1.0f / fmaxf(sqrtf(n1), 1e-8f);
  float i2 = 1.0f / fmaxf(sqrtf(n2), 1e-8f);
#pragma unroll
  for (int c = 0; c < CC; ++c) { d01 += e0[c]*e1[c]; d02 += e0[c]*e2[c]; d12 += e1[c]*e2[c]; }
  sm[0][t] = d01 * i0 * i1;
  sm[1][t] = d02 * i0 * i2;
  sm[2][t] = d12 * i1 * i2;
  __syncthreads();
  for (int s = 128; s; s >>= 1) {
    if (t < s) { sm[0][t] += sm[0][t+s]; sm[1][t] += sm[1][t+s]; sm[2][t] += sm[2][t+s]; }
    __syncthreads();
  }
  if (t == 0) {
    partial[blockIdx.x * 3 + 0] = sm[0][0];
    partial[blockIdx.x * 3 + 1] = sm[1][0];
    partial[blockIdx.x * 3 + 2] = sm[2][0];
  }
}

// ---------------- K7b: S -> threshold -> row softmax -> coef[3] -------------
__global__ void k_coef(const float* __restrict__ partial, float* __restrict__ coef)
{
  if (threadIdx.x != 0) return;
  float S01 = 0, S02 = 0, S12 = 0;
  for (int b = 0; b < NN / 256; ++b) {
    S01 += partial[b * 3 + 0];
    S02 += partial[b * 3 + 1];
    S12 += partial[b * 3 + 2];
  }
  S01 /= (float)NN; S02 /= (float)NN; S12 /= (float)NN;
  float mx = fmaxf(S01, fmaxf(S02, S12));
  float thr = 0.7f * mx;
  float w01 = (S01 > thr) ? S01 : 0.f;
  float w02 = (S02 > thr) ? S02 : 0.f;
  float w12 = (S12 > thr) ? S12 : 0.f;
  // row 0 softmax over edges (0,1),(0,2); row 1 over (1,2); row 2 empty
  float m0 = fmaxf(w01, w02);
  float e01 = expf(w01 - m0), e02 = expf(w02 - m0);
  float s0 = e01 + e02;
  float p01 = e01 / s0, p02 = e02 / s0;
  float p12 = 1.0f;                       // exp(0)/exp(0)
  (void)w12;
  coef[0] = (p01 + p02) / 6.0f;           // rowsum0 + colsum0
  coef[1] = (p12 + p01) / 6.0f;           // rowsum1 + colsum1
  coef[2] = (p02 + p12) / 6.0f;           // rowsum2 + colsum2
}

// ---------------- K7c: agg[n,c] = sum_v coef[v] * E[v,n,c] ------------------
__global__ __launch_bounds__(256) void k_agg(const float* __restrict__ E,
    const float* __restrict__ coef, float* __restrict__ agg)
{
  int idx = blockIdx.x * 256 + threadIdx.x;
  float c0 = coef[0], c1 = coef[1], c2 = coef[2];
  agg[idx] = c0 * E[idx] + c1 * E[NN * CC + idx] + c2 * E[2 * NN * CC + idx];
}

// ---------------------------------------------------------------------------
extern "C" void kernel_launch(void* const* d_in, const int* in_sizes, int n_in,
                              void* d_out, int out_size, void* d_ws, size_t ws_size,
                              hipStream_t stream)
{
  (void)in_sizes; (void)n_in; (void)out_size;
  const float* X         = (const float*)d_in[0];
  const float* A         = (const float*)d_in[1];
  const float* consensus = (const float*)d_in[2];
  const float* W_mlp     = (const float*)d_in[3];
  const float* b_mlp     = (const float*)d_in[4];
  const float* W1        = (const float*)d_in[5];
  const float* b1        = (const float*)d_in[6];
  const float* W2        = (const float*)d_in[7];
  const float* b2        = (const float*)d_in[8];
  float* Eout = (float*)d_out;
  float* aggout = Eout + (size_t)VV * NN * CC;

  char* ws = (char*)d_ws;
  size_t off = 0;
  auto alloc = [&](size_t b) { char* p = ws + off; off += (b + 255) & ~(size_t)255; return p; };
  unsigned long long* mask = (unsigned long long*)alloc((size_t)VV * NN * 64 * 8);
  float*  dinv  = (float*) alloc((size_t)VV * NN * 4);
  bf16_t* Xs_t  = (bf16_t*)alloc((size_t)VV * DD * NN * 2);
  bf16_t* X_bf  = (bf16_t*)alloc((size_t)VV * NN * DD * 2);
  bf16_t* H0    = (bf16_t*)alloc((size_t)VV * NN * DD * 2);
  bf16_t* Wc_t  = (bf16_t*)alloc((size_t)VV * 16 * DD * 2);
  bf16_t* Wm_t  = (bf16_t*)alloc((size_t)VV * 16 * DD * 2);
  float*  bp    = (float*) alloc((size_t)VV * CC * 4);
  float*  Ps_g  = (float*) alloc((size_t)VV * CC * NN * 4);
  float*  mlp_g = (float*) alloc((size_t)VV * NN * CC * 4);
  float*  partial = (float*)alloc((NN / 256) * 3 * 4);
  float*  coef  = (float*) alloc(3 * 4);
  if (off > ws_size) return;   // workspace too small: leave output poisoned (visible failure)

  k_mask <<<VV * NN / 4, 256, 0, stream>>>(A, mask, dinv);
  k_xpose<<<dim3(NN / 64, DD / 64, VV), 256, 0, stream>>>(X, dinv, Xs_t, X_bf);
  k_wc   <<<(VV * 513 + 3) / 4, 256, 0, stream>>>(W1, b1, W2, Wc_t, bp);
  k_wm   <<<(VV * DD + 255) / 256, 256, 0, stream>>>(W_mlp, Wm_t);
  k_gemm <<<dim3(DD / BN, NN / BM, VV), 256, 0, stream>>>((const unsigned*)mask, Xs_t, dinv, H0);
  k_small<<<dim3(NN / 64, VV), 256, 0, stream>>>(H0, X_bf, Wc_t, Wm_t, bp, b_mlp, dinv, Ps_g, mlp_g);
  k_spmm <<<dim3(NN / 32, VV), 256, 0, stream>>>(mask, Ps_g, mlp_g, consensus, b2, dinv, Eout);
  k_sim  <<<NN / 256, 256, 0, stream>>>(Eout, partial);
  k_coef <<<1, 64, 0, stream>>>(partial, coef);
  k_agg  <<<NN * CC / 256, 256, 0, stream>>>(Eout, coef, aggout);
}